// Round 2
// baseline (3845.538 us; speedup 1.0000x reference)
//
#include <hip/hip_runtime.h>
#include <hip/hip_bf16.h>

#define E 4096
#define M 12
#define C 64
#define D 64
#define M0 5
#define XD 64
#define EC 128
#define MAIN (M*C*D)        // 49152
#define EXTRA (M0*C*XD)     // 20480
#define TOTAL (MAIN+EXTRA)  // 69632

__device__ __forceinline__ float silu_f(float v) {
    return v / (1.0f + __expf(-v));
}

// ---------------- Kernel 1: h2 = silu(silu(x_edge@W1+b1)@W2+b2) ----------------
__global__ __launch_bounds__(256) void mlp_kernel(
    const float* __restrict__ x_edge, const float* __restrict__ W1,
    const float* __restrict__ b1, const float* __restrict__ W2,
    const float* __restrict__ b2, float* __restrict__ h2out)
{
    __shared__ float xe[16][128];
    __shared__ float h1s[16][128];
    const int t  = threadIdx.x;
    const int b0 = blockIdx.x * 16;
    const int j  = t & 127;
    const int rh = t >> 7;   // 0/1

    #pragma unroll
    for (int i = 0; i < 8; ++i) {
        int lin = t + i * 256;
        int r = lin >> 7, k = lin & 127;
        xe[r][k] = x_edge[(size_t)(b0 + r) * EC + k];
    }
    __syncthreads();

    {   // layer 1
        float acc[8];
        float bb = b1[j];
        #pragma unroll
        for (int it = 0; it < 8; ++it) acc[it] = bb;
        for (int k = 0; k < 128; ++k) {
            float w = W1[k * EC + j];
            #pragma unroll
            for (int it = 0; it < 8; ++it)
                acc[it] += xe[rh + it * 2][k] * w;
        }
        #pragma unroll
        for (int it = 0; it < 8; ++it) h1s[rh + it * 2][j] = silu_f(acc[it]);
    }
    __syncthreads();
    {   // layer 2
        float acc[8];
        float bb = b2[j];
        #pragma unroll
        for (int it = 0; it < 8; ++it) acc[it] = bb;
        for (int k = 0; k < 128; ++k) {
            float w = W2[k * EC + j];
            #pragma unroll
            for (int it = 0; it < 8; ++it)
                acc[it] += h1s[rh + it * 2][k] * w;
        }
        #pragma unroll
        for (int it = 0; it < 8; ++it)
            h2out[(size_t)(b0 + rh + it * 2) * EC + j] = silu_f(acc[it]);
    }
}

// ---------------- Kernel 2: out[b,m,d] = sum_c x[b,m,c]*(h2[b]·W3[:,m,c,d]+b3[m,c,d]) ----
// grid (E/64, M), 256 threads. Per thread: 4 b x 4 d accumulators.
__global__ __launch_bounds__(256) void main_kernel(
    const float* __restrict__ x, const float* __restrict__ h2,
    const float* __restrict__ W3, const float* __restrict__ b3,
    float* __restrict__ out)
{
    __shared__ float xs[64][65];     // x tile, padded
    __shared__ float h2s[64][129];   // h2 tile, padded
    const int t  = threadIdx.x;
    const int b0 = blockIdx.x * 64;
    const int m  = blockIdx.y;

    #pragma unroll
    for (int i = 0; i < 16; ++i) {
        int lin = t + i * 256;
        int r = lin >> 6, c = lin & 63;
        xs[r][c] = x[(size_t)(b0 + r) * (M * C) + m * C + c];
    }
    #pragma unroll
    for (int i = 0; i < 32; ++i) {
        int lin = t + i * 256;
        int r = lin >> 7, k = lin & 127;
        h2s[r][k] = h2[(size_t)(b0 + r) * EC + k];
    }
    __syncthreads();

    const int w  = t >> 6;    // wave id -> b sub-tile of 16
    const int l  = t & 63;
    const int bg = l >> 4;    // 0..3
    const int dg = l & 15;    // 0..15
    const int wb = w * 16;

    float acc[4][4];
    #pragma unroll
    for (int a = 0; a < 4; ++a)
        #pragma unroll
        for (int b = 0; b < 4; ++b) acc[a][b] = 0.f;

    const float* W3m = W3 + (size_t)m * (C * D);
    const float* b3m = b3 + (size_t)m * (C * D);

    for (int k = 0; k <= 128; ++k) {
        float hk[4];
        const float* wrow;
        if (k < 128) {
            #pragma unroll
            for (int jb = 0; jb < 4; ++jb)
                hk[jb] = h2s[wb + bg * 4 + jb][k];
            wrow = W3m + (size_t)k * TOTAL;
        } else {   // bias pass
            #pragma unroll
            for (int jb = 0; jb < 4; ++jb) hk[jb] = 1.0f;
            wrow = b3m;
        }
        #pragma unroll 4
        for (int c = 0; c < 64; ++c) {
            float4 w3v = *reinterpret_cast<const float4*>(wrow + c * D + dg * 4);
            #pragma unroll
            for (int jb = 0; jb < 4; ++jb) {
                float p = hk[jb] * xs[wb + bg * 4 + jb][c];
                acc[jb][0] += p * w3v.x;
                acc[jb][1] += p * w3v.y;
                acc[jb][2] += p * w3v.z;
                acc[jb][3] += p * w3v.w;
            }
        }
    }

    #pragma unroll
    for (int jb = 0; jb < 4; ++jb) {
        int b = b0 + wb + bg * 4 + jb;
        float4 v = make_float4(acc[jb][0], acc[jb][1], acc[jb][2], acc[jb][3]);
        *reinterpret_cast<float4*>(out + (size_t)b * (M * D) + m * D + dg * 4) = v;
    }
}

// ---------------- Kernel 3: gating[b,d] = sum_{m<5,c} x[b,m,c]*(h2[b]·W3e+b3e) ----------
// grid E/16, 256 threads. Per thread: 1 b x 4 d.
__global__ __launch_bounds__(256) void gate_kernel(
    const float* __restrict__ x, const float* __restrict__ h2,
    const float* __restrict__ W3, const float* __restrict__ b3,
    float* __restrict__ gate)
{
    __shared__ float xs[M0][16][65];
    __shared__ float h2s[16][129];
    const int t  = threadIdx.x;
    const int b0 = blockIdx.x * 16;

    for (int lin = t; lin < M0 * 16 * 64; lin += 256) {
        int mm  = lin / (16 * 64);
        int rem = lin - mm * (16 * 64);
        int r = rem >> 6, c = rem & 63;
        xs[mm][r][c] = x[(size_t)(b0 + r) * (M * C) + mm * C + c];
    }
    for (int lin = t; lin < 16 * 128; lin += 256) {
        int r = lin >> 7, k = lin & 127;
        h2s[r][k] = h2[(size_t)(b0 + r) * EC + k];
    }
    __syncthreads();

    const int w  = t >> 6;
    const int l  = t & 63;
    const int bg = l >> 4;
    const int dg = l & 15;
    const int b  = w * 4 + bg;   // 0..15

    float acc[4] = {0.f, 0.f, 0.f, 0.f};

    for (int k = 0; k <= 128; ++k) {
        float hk;
        const float* wbase;
        if (k < 128) {
            hk = h2s[b][k];
            wbase = W3 + (size_t)k * TOTAL + MAIN;
        } else {
            hk = 1.0f;
            wbase = b3 + MAIN;
        }
        #pragma unroll
        for (int mm = 0; mm < M0; ++mm) {
            const float* wrow = wbase + mm * (C * XD);
            #pragma unroll 4
            for (int c = 0; c < 64; ++c) {
                float4 w3v = *reinterpret_cast<const float4*>(wrow + c * XD + dg * 4);
                float p = hk * xs[mm][b][c];
                acc[0] += p * w3v.x;
                acc[1] += p * w3v.y;
                acc[2] += p * w3v.z;
                acc[3] += p * w3v.w;
            }
        }
    }

    float4 v = make_float4(acc[0], acc[1], acc[2], acc[3]);
    *reinterpret_cast<float4*>(gate + (size_t)(b0 + b) * XD + dg * 4) = v;
}

extern "C" void kernel_launch(void* const* d_in, const int* in_sizes, int n_in,
                              void* d_out, int out_size, void* d_ws, size_t ws_size,
                              hipStream_t stream)
{
    const float* x      = (const float*)d_in[0];
    const float* x_edge = (const float*)d_in[1];
    const float* W1     = (const float*)d_in[2];
    const float* b1     = (const float*)d_in[3];
    const float* W2     = (const float*)d_in[4];
    const float* b2     = (const float*)d_in[5];
    const float* W3     = (const float*)d_in[6];
    const float* b3     = (const float*)d_in[7];

    float* out  = (float*)d_out;
    float* gate = out + (size_t)E * M * D;   // outputs concatenated flat
    float* h2   = (float*)d_ws;              // E*EC f32 = 2 MB scratch

    mlp_kernel <<<E / 16, 256, 0, stream>>>(x_edge, W1, b1, W2, b2, h2);
    main_kernel<<<dim3(E / 64, M), 256, 0, stream>>>(x, h2, W3, b3, out);
    gate_kernel<<<E / 16, 256, 0, stream>>>(x, h2, W3, b3, gate);
}

// Round 3
// 2011.981 us; speedup vs baseline: 1.9113x; 1.9113x over previous
//
#include <hip/hip_runtime.h>
#include <hip/hip_bf16.h>

#define E 4096
#define M 12
#define C 64
#define D 64
#define M0 5
#define XD 64
#define EC 128
#define MAIN (M*C*D)        // 49152
#define EXTRA (M0*C*XD)     // 20480
#define TOTAL (MAIN+EXTRA)  // 69632

__device__ __forceinline__ float silu_f(float v) {
    return v / (1.0f + __expf(-v));
}

// ---------------- Kernel 1: h2 = silu(silu(x_edge@W1+b1)@W2+b2) ----------------
__global__ __launch_bounds__(256) void mlp_kernel(
    const float* __restrict__ x_edge, const float* __restrict__ W1,
    const float* __restrict__ b1, const float* __restrict__ W2,
    const float* __restrict__ b2, float* __restrict__ h2out)
{
    __shared__ float xe[16][128];
    __shared__ float h1s[16][128];
    const int t  = threadIdx.x;
    const int b0 = blockIdx.x * 16;
    const int j  = t & 127;
    const int rh = t >> 7;   // 0/1

    #pragma unroll
    for (int i = 0; i < 8; ++i) {
        int lin = t + i * 256;
        int r = lin >> 7, k = lin & 127;
        xe[r][k] = x_edge[(size_t)(b0 + r) * EC + k];
    }
    __syncthreads();

    {   // layer 1
        float acc[8];
        float bb = b1[j];
        #pragma unroll
        for (int it = 0; it < 8; ++it) acc[it] = bb;
        for (int k = 0; k < 128; ++k) {
            float w = W1[k * EC + j];
            #pragma unroll
            for (int it = 0; it < 8; ++it)
                acc[it] += xe[rh + it * 2][k] * w;
        }
        #pragma unroll
        for (int it = 0; it < 8; ++it) h1s[rh + it * 2][j] = silu_f(acc[it]);
    }
    __syncthreads();
    {   // layer 2
        float acc[8];
        float bb = b2[j];
        #pragma unroll
        for (int it = 0; it < 8; ++it) acc[it] = bb;
        for (int k = 0; k < 128; ++k) {
            float w = W2[k * EC + j];
            #pragma unroll
            for (int it = 0; it < 8; ++it)
                acc[it] += h1s[rh + it * 2][k] * w;
        }
        #pragma unroll
        for (int it = 0; it < 8; ++it)
            h2out[(size_t)(b0 + rh + it * 2) * EC + j] = silu_f(acc[it]);
    }
}

// ---------------- Kernel 2: out[b,m,d] = sum_c x[b,m,c]*(h2[b]·W3[:,m,c,d]+b3[m,c,d]) ----
// grid (E/64, M), 256 threads. Per thread: 4 b x 4 d accumulators.
__global__ __launch_bounds__(256) void main_kernel(
    const float* __restrict__ x, const float* __restrict__ h2,
    const float* __restrict__ W3, const float* __restrict__ b3,
    float* __restrict__ out)
{
    __shared__ float xs[64][65];     // x tile, padded
    __shared__ float h2s[64][129];   // h2 tile, padded
    const int t  = threadIdx.x;
    const int b0 = blockIdx.x * 64;
    const int m  = blockIdx.y;

    #pragma unroll
    for (int i = 0; i < 16; ++i) {
        int lin = t + i * 256;
        int r = lin >> 6, c = lin & 63;
        xs[r][c] = x[(size_t)(b0 + r) * (M * C) + m * C + c];
    }
    #pragma unroll
    for (int i = 0; i < 32; ++i) {
        int lin = t + i * 256;
        int r = lin >> 7, k = lin & 127;
        h2s[r][k] = h2[(size_t)(b0 + r) * EC + k];
    }
    __syncthreads();

    const int w  = t >> 6;    // wave id -> b sub-tile of 16
    const int l  = t & 63;
    const int bg = l >> 4;    // 0..3
    const int dg = l & 15;    // 0..15
    const int wb = w * 16;

    float acc[4][4];
    #pragma unroll
    for (int a = 0; a < 4; ++a)
        #pragma unroll
        for (int b = 0; b < 4; ++b) acc[a][b] = 0.f;

    const float* W3m = W3 + (size_t)m * (C * D);
    const float* b3m = b3 + (size_t)m * (C * D);

    for (int k = 0; k <= 128; ++k) {
        float hk[4];
        const float* wrow;
        if (k < 128) {
            #pragma unroll
            for (int jb = 0; jb < 4; ++jb)
                hk[jb] = h2s[wb + bg * 4 + jb][k];
            wrow = W3m + (size_t)k * TOTAL;
        } else {   // bias pass
            #pragma unroll
            for (int jb = 0; jb < 4; ++jb) hk[jb] = 1.0f;
            wrow = b3m;
        }
        #pragma unroll 4
        for (int c = 0; c < 64; ++c) {
            float4 w3v = *reinterpret_cast<const float4*>(wrow + c * D + dg * 4);
            #pragma unroll
            for (int jb = 0; jb < 4; ++jb) {
                float p = hk[jb] * xs[wb + bg * 4 + jb][c];
                acc[jb][0] += p * w3v.x;
                acc[jb][1] += p * w3v.y;
                acc[jb][2] += p * w3v.z;
                acc[jb][3] += p * w3v.w;
            }
        }
    }

    #pragma unroll
    for (int jb = 0; jb < 4; ++jb) {
        int b = b0 + wb + bg * 4 + jb;
        float4 v = make_float4(acc[jb][0], acc[jb][1], acc[jb][2], acc[jb][3]);
        *reinterpret_cast<float4*>(out + (size_t)b * (M * D) + m * D + dg * 4) = v;
    }
}

// ---------------- Kernel 3: gating partial for one m ----------
// grid (E/16, M0), 256 threads. Per thread: 1 b x 4 d. atomicAdd into zeroed gate.
__global__ __launch_bounds__(256) void gate_kernel(
    const float* __restrict__ x, const float* __restrict__ h2,
    const float* __restrict__ W3, const float* __restrict__ b3,
    float* __restrict__ gate)
{
    __shared__ float xs[16][65];
    __shared__ float h2s[16][129];
    const int t  = threadIdx.x;
    const int b0 = blockIdx.x * 16;
    const int mm = blockIdx.y;

    #pragma unroll
    for (int i = 0; i < 4; ++i) {
        int lin = t + i * 256;
        int r = lin >> 6, c = lin & 63;
        xs[r][c] = x[(size_t)(b0 + r) * (M * C) + mm * C + c];
    }
    #pragma unroll
    for (int i = 0; i < 8; ++i) {
        int lin = t + i * 256;
        int r = lin >> 7, k = lin & 127;
        h2s[r][k] = h2[(size_t)(b0 + r) * EC + k];
    }
    __syncthreads();

    const int w  = t >> 6;
    const int l  = t & 63;
    const int bg = l >> 4;
    const int dg = l & 15;
    const int b  = w * 4 + bg;   // 0..15

    float acc[4] = {0.f, 0.f, 0.f, 0.f};

    const float* W3e = W3 + (size_t)MAIN + (size_t)mm * (C * XD);
    const float* b3e = b3 + (size_t)MAIN + (size_t)mm * (C * XD);

    for (int k = 0; k <= 128; ++k) {
        float hk;
        const float* wrow;
        if (k < 128) {
            hk = h2s[b][k];
            wrow = W3e + (size_t)k * TOTAL;
        } else {
            hk = 1.0f;
            wrow = b3e;
        }
        #pragma unroll 8
        for (int c = 0; c < 64; ++c) {
            float4 w3v = *reinterpret_cast<const float4*>(wrow + c * XD + dg * 4);
            float p = hk * xs[b][c];
            acc[0] += p * w3v.x;
            acc[1] += p * w3v.y;
            acc[2] += p * w3v.z;
            acc[3] += p * w3v.w;
        }
    }

    float* gp = gate + (size_t)(b0 + b) * XD + dg * 4;
    atomicAdd(gp + 0, acc[0]);
    atomicAdd(gp + 1, acc[1]);
    atomicAdd(gp + 2, acc[2]);
    atomicAdd(gp + 3, acc[3]);
}

extern "C" void kernel_launch(void* const* d_in, const int* in_sizes, int n_in,
                              void* d_out, int out_size, void* d_ws, size_t ws_size,
                              hipStream_t stream)
{
    const float* x      = (const float*)d_in[0];
    const float* x_edge = (const float*)d_in[1];
    const float* W1     = (const float*)d_in[2];
    const float* b1     = (const float*)d_in[3];
    const float* W2     = (const float*)d_in[4];
    const float* b2     = (const float*)d_in[5];
    const float* W3     = (const float*)d_in[6];
    const float* b3     = (const float*)d_in[7];

    float* out  = (float*)d_out;
    float* gate = out + (size_t)E * M * D;   // outputs concatenated flat
    float* h2   = (float*)d_ws;              // E*EC f32 = 2 MB scratch

    // zero the gate region (atomic accumulation target); graph-capturable
    hipMemsetAsync(gate, 0, (size_t)E * XD * sizeof(float), stream);

    mlp_kernel <<<E / 16, 256, 0, stream>>>(x_edge, W1, b1, W2, b2, h2);
    main_kernel<<<dim3(E / 64, M), 256, 0, stream>>>(x, h2, W3, b3, out);
    gate_kernel<<<dim3(E / 16, M0), 256, 0, stream>>>(x, h2, W3, b3, gate);
}

// Round 4
// 227.436 us; speedup vs baseline: 16.9082x; 8.8464x over previous
//
#include <hip/hip_runtime.h>
#include <hip/hip_bf16.h>

#define E 4096
#define M 12
#define C 64
#define D 64
#define M0 5
#define XD 64
#define EC 128
#define MAIN (M*C*D)        // 49152
#define EXTRA (M0*C*XD)     // 20480
#define TOTAL (MAIN+EXTRA)  // 69632 = 17*4096
#define NSLICE 17
#define KDIM 8256           // per-slice K = 129*64 (129 = 128 k + bias row)

typedef float  f32x4  __attribute__((ext_vector_type(4)));
typedef __bf16 bf16x8 __attribute__((ext_vector_type(8)));
typedef unsigned int u32x4 __attribute__((ext_vector_type(4)));

__device__ __forceinline__ float silu_f(float v) { return v / (1.0f + __expf(-v)); }

__device__ __forceinline__ unsigned short f2bf(float f) {
    unsigned u = __builtin_bit_cast(unsigned, f);
    u += 0x7FFFu + ((u >> 16) & 1u);          // RNE
    return (unsigned short)(u >> 16);
}
__device__ __forceinline__ unsigned pack2(float a, float b) {
    return (unsigned)f2bf(a) | ((unsigned)f2bf(b) << 16);
}
__device__ __forceinline__ float asf(unsigned u) { return __builtin_bit_cast(float, u); }

// ---------- Kernel 1: MLP -> h2^T in bf16, layout [129][E] (row 128 = ones) ----------
__global__ __launch_bounds__(256) void mlp_kernel(
    const float* __restrict__ x_edge, const float* __restrict__ W1,
    const float* __restrict__ b1, const float* __restrict__ W2,
    const float* __restrict__ b2, unsigned short* __restrict__ h2t)
{
    __shared__ float xe[16][128];
    __shared__ float h1s[16][128];
    const int t  = threadIdx.x;
    const int b0 = blockIdx.x * 16;
    const int j  = t & 127;
    const int rh = t >> 7;

    #pragma unroll
    for (int i = 0; i < 8; ++i) {
        int lin = t + i * 256;
        int r = lin >> 7, k = lin & 127;
        xe[r][k] = x_edge[(size_t)(b0 + r) * EC + k];
    }
    __syncthreads();
    {
        float acc[8];
        float bb = b1[j];
        #pragma unroll
        for (int it = 0; it < 8; ++it) acc[it] = bb;
        for (int k = 0; k < 128; ++k) {
            float w = W1[k * EC + j];
            #pragma unroll
            for (int it = 0; it < 8; ++it) acc[it] += xe[rh + it * 2][k] * w;
        }
        #pragma unroll
        for (int it = 0; it < 8; ++it) h1s[rh + it * 2][j] = silu_f(acc[it]);
    }
    __syncthreads();
    {
        float acc[8];
        float bb = b2[j];
        #pragma unroll
        for (int it = 0; it < 8; ++it) acc[it] = bb;
        for (int k = 0; k < 128; ++k) {
            float w = W2[k * EC + j];
            #pragma unroll
            for (int it = 0; it < 8; ++it) acc[it] += h1s[rh + it * 2][k] * w;
        }
        #pragma unroll
        for (int it = 0; it < 8; ++it)
            h2t[(size_t)j * E + (b0 + rh + it * 2)] = f2bf(silu_f(acc[it]));
    }
    if (t < 16) h2t[(size_t)128 * E + b0 + t] = 0x3F80;   // bias row = 1.0 bf16
}

// ---------- Kernel 2: W3T[s*64+d][k*64+c] = bf16(W3[k][s*4096+c*64+d]) (k=128 -> b3) ----
__global__ __launch_bounds__(256) void w3t_kernel(
    const float* __restrict__ W3, const float* __restrict__ b3,
    unsigned short* __restrict__ w3t)
{
    const int k = blockIdx.x;   // 0..128
    const int s = blockIdx.y;   // 0..16
    __shared__ float tile[64][68];
    const int t = threadIdx.x;
    const float* src = ((k < 128) ? (W3 + (size_t)k * TOTAL) : b3) + s * 4096;

    const int c  = t >> 2;
    const int dp = (t & 3) * 16;
    #pragma unroll
    for (int i = 0; i < 4; ++i) {
        float4 v = *reinterpret_cast<const float4*>(src + c * 64 + dp + i * 4);
        *reinterpret_cast<float4*>(&tile[c][dp + i * 4]) = v;
    }
    __syncthreads();

    const int d  = t >> 2;
    const int cp = (t & 3) * 16;
    unsigned u[8];
    #pragma unroll
    for (int i = 0; i < 8; ++i)
        u[i] = pack2(tile[cp + 2 * i][d], tile[cp + 2 * i + 1][d]);
    unsigned short* dst = w3t + (size_t)(s * 64 + d) * KDIM + k * 64 + cp;
    *reinterpret_cast<u32x4*>(dst)     = u32x4{u[0], u[1], u[2], u[3]};
    *reinterpret_cast<u32x4*>(dst + 8) = u32x4{u[4], u[5], u[6], u[7]};
}

// ---------- Kernel 3: fused weight-gen + contraction (MFMA) ----------
// grid (16, 17, 2): bx -> 256 b-rows, s -> slice, kz -> K half.
// 4 waves x 64 rows. A = x frags (regs), B = W3T chunk (global->regs), h2 via LDS.
__global__ __launch_bounds__(256, 2) void gemm_kernel(
    const float* __restrict__ x, const unsigned short* __restrict__ h2t,
    const unsigned short* __restrict__ w3t,
    float* __restrict__ out, float* __restrict__ out2, float* __restrict__ gatep)
{
    __shared__ __align__(16) unsigned short h2s[65 * 256];
    const int t  = threadIdx.x;
    const int w  = t >> 6;
    const int l  = t & 63;
    const int p  = l >> 4;
    const int lr = l & 15;
    const int bx = blockIdx.x;
    const int s  = blockIdx.y;
    const int kz = blockIdx.z;
    const int k0 = kz * 65;
    const int nk = 65 - kz;             // 65 or 64
    const int b0 = bx * 256;
    const int m  = (s < 12) ? s : (s - 12);

    // stage h2^T tile: rows k0..k0+nk-1, cols b0..b0+255, LDS row = 512B
    {
        const char* h2g = (const char*)(h2t + (size_t)k0 * E + b0);
        const int total = nk * 512;
        for (int r = 0; r < 9; ++r) {
            int lin = r * 4096 + t * 16;
            if (lin < total) {
                int kl = lin >> 9, off = lin & 511;
                *reinterpret_cast<u32x4*>((char*)h2s + lin) =
                    *reinterpret_cast<const u32x4*>(h2g + (size_t)kl * (E * 2) + off);
            }
        }
    }

    // A fragments: x rows for this wave, bf16-packed, live whole kernel
    u32x4 xa[4][2];
    #pragma unroll
    for (int rf = 0; rf < 4; ++rf)
        #pragma unroll
        for (int s2 = 0; s2 < 2; ++s2) {
            const float* xp = x + (size_t)(b0 + w * 64 + rf * 16 + lr) * (M * C)
                              + m * 64 + s2 * 32 + p * 8;
            float4 a = *reinterpret_cast<const float4*>(xp);
            float4 b = *reinterpret_cast<const float4*>(xp + 4);
            xa[rf][s2] = u32x4{pack2(a.x, a.y), pack2(a.z, a.w),
                               pack2(b.x, b.y), pack2(b.z, b.w)};
        }
    __syncthreads();

    // B voffsets (bytes) per col-frag
    const char* wbase = (const char*)w3t;
    size_t vb[4];
    #pragma unroll
    for (int cf = 0; cf < 4; ++cf)
        vb[cf] = ((size_t)(s * 64 + cf * 16 + lr) * KDIM + (size_t)k0 * 64 + p * 8) * 2;

    f32x4 acc[4][4];
    #pragma unroll
    for (int a = 0; a < 4; ++a)
        #pragma unroll
        for (int b = 0; b < 4; ++b) acc[a][b] = f32x4{0.f, 0.f, 0.f, 0.f};
    const f32x4 zf = {0.f, 0.f, 0.f, 0.f};

    u32x4 Ba[4][2], Bb[4][2];

#define LOADB(B, kr)                                                              \
    _Pragma("unroll")                                                             \
    for (int cf = 0; cf < 4; ++cf) {                                              \
        _Pragma("unroll")                                                         \
        for (int s2 = 0; s2 < 2; ++s2)                                            \
            B[cf][s2] = *reinterpret_cast<const u32x4*>(                          \
                wbase + vb[cf] + (size_t)(kr) * 128 + s2 * 64);                   \
    }

#define COMPB(B, kr)                                                              \
    _Pragma("unroll")                                                             \
    for (int rf = 0; rf < 4; ++rf) {                                              \
        const char* hp = (const char*)h2s + (kr) * 512 + (w * 64 + rf * 16 + p * 4) * 2; \
        unsigned h01 = *reinterpret_cast<const unsigned*>(hp);                    \
        unsigned h23 = *reinterpret_cast<const unsigned*>(hp + 4);                \
        float h0 = asf(h01 << 16), h1 = asf(h01 & 0xFFFF0000u);                   \
        float h2v = asf(h23 << 16), h3 = asf(h23 & 0xFFFF0000u);                  \
        _Pragma("unroll")                                                         \
        for (int cf = 0; cf < 4; ++cf) {                                          \
            f32x4 tt = __builtin_amdgcn_mfma_f32_16x16x32_bf16(                   \
                __builtin_bit_cast(bf16x8, xa[rf][0]),                            \
                __builtin_bit_cast(bf16x8, B[cf][0]), zf, 0, 0, 0);               \
            tt = __builtin_amdgcn_mfma_f32_16x16x32_bf16(                         \
                __builtin_bit_cast(bf16x8, xa[rf][1]),                            \
                __builtin_bit_cast(bf16x8, B[cf][1]), tt, 0, 0, 0);               \
            acc[rf][cf][0] += h0 * tt[0];                                         \
            acc[rf][cf][1] += h1 * tt[1];                                         \
            acc[rf][cf][2] += h2v * tt[2];                                        \
            acc[rf][cf][3] += h3 * tt[3];                                         \
        }                                                                         \
    }

    LOADB(Ba, 0);
    for (int kk = 0; kk < nk; kk += 2) {
        const bool has1 = (kk + 1 < nk);
        if (has1) { LOADB(Bb, kk + 1); }
        COMPB(Ba, kk);
        if (has1) {
            if (kk + 2 < nk) { LOADB(Ba, kk + 2); }
            COMPB(Bb, kk + 1);
        }
    }
#undef LOADB
#undef COMPB

    // store: main (s<12): kz0 -> out, kz1 -> out2. gate (s>=12): gatep[(s-12)*2+kz]
    if (s < 12) {
        float* ob = (kz == 0) ? out : out2;
        #pragma unroll
        for (int rf = 0; rf < 4; ++rf)
            #pragma unroll
            for (int cf = 0; cf < 4; ++cf)
                #pragma unroll
                for (int r = 0; r < 4; ++r) {
                    int b = b0 + w * 64 + rf * 16 + p * 4 + r;
                    int d = cf * 16 + lr;
                    ob[(size_t)b * (M * D) + s * D + d] = acc[rf][cf][r];
                }
    } else {
        float* gp = gatep + (size_t)((s - 12) * 2 + kz) * (E * 64);
        #pragma unroll
        for (int rf = 0; rf < 4; ++rf)
            #pragma unroll
            for (int cf = 0; cf < 4; ++cf)
                #pragma unroll
                for (int r = 0; r < 4; ++r) {
                    int b = b0 + w * 64 + rf * 16 + p * 4 + r;
                    int d = cf * 16 + lr;
                    gp[(size_t)b * 64 + d] = acc[rf][cf][r];
                }
    }
}

// ---------- Kernel 4: out += out2 (main), gate = sum of 10 partials ----------
__global__ __launch_bounds__(256) void reduce_kernel(
    float* __restrict__ out, const float* __restrict__ out2,
    const float* __restrict__ gatep)
{
    const int MAIN4 = E * M * D / 4;     // 786432
    int i = blockIdx.x * 256 + threadIdx.x;
    if (i < MAIN4) {
        float4 a = reinterpret_cast<float4*>(out)[i];
        float4 b = reinterpret_cast<const float4*>(out2)[i];
        a.x += b.x; a.y += b.y; a.z += b.z; a.w += b.w;
        reinterpret_cast<float4*>(out)[i] = a;
    } else {
        int j = i - MAIN4;               // < E*64/4 = 65536
        const float4* g4 = reinterpret_cast<const float4*>(gatep);
        float4 sum = make_float4(0.f, 0.f, 0.f, 0.f);
        #pragma unroll
        for (int q = 0; q < 10; ++q) {
            float4 v = g4[(size_t)q * 65536 + j];
            sum.x += v.x; sum.y += v.y; sum.z += v.z; sum.w += v.w;
        }
        reinterpret_cast<float4*>(out + (size_t)E * M * D)[j] = sum;
    }
}

extern "C" void kernel_launch(void* const* d_in, const int* in_sizes, int n_in,
                              void* d_out, int out_size, void* d_ws, size_t ws_size,
                              hipStream_t stream)
{
    const float* x      = (const float*)d_in[0];
    const float* x_edge = (const float*)d_in[1];
    const float* W1     = (const float*)d_in[2];
    const float* b1     = (const float*)d_in[3];
    const float* W2     = (const float*)d_in[4];
    const float* b2     = (const float*)d_in[5];
    const float* W3     = (const float*)d_in[6];
    const float* b3     = (const float*)d_in[7];

    float* out = (float*)d_out;

    // ws layout (bytes): W3T 17,965,056 | h2t 1,056,768 | out2 12,582,912 | gatep 10,485,760
    char* ws = (char*)d_ws;
    unsigned short* w3t  = (unsigned short*)ws;
    unsigned short* h2t  = (unsigned short*)(ws + 17965056);
    float*          out2 = (float*)(ws + 19021824);
    float*          gatep= (float*)(ws + 31604736);

    mlp_kernel<<<E / 16, 256, 0, stream>>>(x_edge, W1, b1, W2, b2, h2t);
    w3t_kernel<<<dim3(129, NSLICE), 256, 0, stream>>>(W3, b3, w3t);
    gemm_kernel<<<dim3(16, NSLICE, 2), 256, 0, stream>>>(x, h2t, w3t, out, out2, gatep);
    reduce_kernel<<<3328, 256, 0, stream>>>(out, out2, gatep);
}

// Round 5
// 140.854 us; speedup vs baseline: 27.3015x; 1.6147x over previous
//
#include <hip/hip_runtime.h>
#include <hip/hip_bf16.h>

#define E 4096
#define M 12
#define C 64
#define D 64
#define M0 5
#define XD 64
#define EC 128
#define MAIN (M*C*D)        // 49152
#define EXTRA (M0*C*XD)     // 20480
#define TOTAL (MAIN+EXTRA)  // 69632 = 17*4096
#define NSLICE 17
#define KDIM 8256           // per-slice K = 129*64

typedef float  f32x4  __attribute__((ext_vector_type(4)));
typedef __bf16 bf16x8 __attribute__((ext_vector_type(8)));
typedef unsigned int u32x4 __attribute__((ext_vector_type(4)));
typedef unsigned int u32x2 __attribute__((ext_vector_type(2)));

typedef const __attribute__((address_space(1))) void gvoid;
typedef __attribute__((address_space(3))) void lvoid;

__device__ __forceinline__ float silu_f(float v) { return v / (1.0f + __expf(-v)); }

__device__ __forceinline__ unsigned short f2bf(float f) {
    unsigned u = __builtin_bit_cast(unsigned, f);
    u += 0x7FFFu + ((u >> 16) & 1u);          // RNE
    return (unsigned short)(u >> 16);
}
__device__ __forceinline__ unsigned pack2(float a, float b) {
    return (unsigned)f2bf(a) | ((unsigned)f2bf(b) << 16);
}
__device__ __forceinline__ float asf(unsigned u) { return __builtin_bit_cast(float, u); }

// ---------- Kernel 1: MLP -> h2^T bf16 [129][E] (row 128 = ones) ----------
__global__ __launch_bounds__(256) void mlp_kernel(
    const float* __restrict__ x_edge, const float* __restrict__ W1,
    const float* __restrict__ b1, const float* __restrict__ W2,
    const float* __restrict__ b2, unsigned short* __restrict__ h2t)
{
    __shared__ float xe[16][128];
    __shared__ float h1s[16][128];
    const int t  = threadIdx.x;
    const int b0 = blockIdx.x * 16;
    const int j  = t & 127;
    const int rh = t >> 7;

    #pragma unroll
    for (int i = 0; i < 8; ++i) {
        int lin = t + i * 256;
        int r = lin >> 7, k = lin & 127;
        xe[r][k] = x_edge[(size_t)(b0 + r) * EC + k];
    }
    __syncthreads();
    {
        float acc[8];
        float bb = b1[j];
        #pragma unroll
        for (int it = 0; it < 8; ++it) acc[it] = bb;
        for (int k = 0; k < 128; ++k) {
            float w = W1[k * EC + j];
            #pragma unroll
            for (int it = 0; it < 8; ++it) acc[it] += xe[rh + it * 2][k] * w;
        }
        #pragma unroll
        for (int it = 0; it < 8; ++it) h1s[rh + it * 2][j] = silu_f(acc[it]);
    }
    __syncthreads();
    {
        float acc[8];
        float bb = b2[j];
        #pragma unroll
        for (int it = 0; it < 8; ++it) acc[it] = bb;
        for (int k = 0; k < 128; ++k) {
            float w = W2[k * EC + j];
            #pragma unroll
            for (int it = 0; it < 8; ++it) acc[it] += h1s[rh + it * 2][k] * w;
        }
        #pragma unroll
        for (int it = 0; it < 8; ++it)
            h2t[(size_t)j * E + (b0 + rh + it * 2)] = f2bf(silu_f(acc[it]));
    }
    if (t < 16) h2t[(size_t)128 * E + b0 + t] = 0x3F80;   // 1.0 bf16
}

// ---------- Kernel 2: W3T[s*64+d][k*64+c] = bf16(W3[k][s*4096+c*64+d]) ----------
__global__ __launch_bounds__(256) void w3t_kernel(
    const float* __restrict__ W3, const float* __restrict__ b3,
    unsigned short* __restrict__ w3t)
{
    const int k = blockIdx.x;   // 0..128
    const int s = blockIdx.y;   // 0..16
    __shared__ float tile[64][68];
    const int t = threadIdx.x;
    const float* src = ((k < 128) ? (W3 + (size_t)k * TOTAL) : b3) + s * 4096;

    const int c  = t >> 2;
    const int dp = (t & 3) * 16;
    #pragma unroll
    for (int i = 0; i < 4; ++i) {
        float4 v = *reinterpret_cast<const float4*>(src + c * 64 + dp + i * 4);
        *reinterpret_cast<float4*>(&tile[c][dp + i * 4]) = v;
    }
    __syncthreads();

    const int d  = t >> 2;
    const int cp = (t & 3) * 16;
    unsigned u[8];
    #pragma unroll
    for (int i = 0; i < 8; ++i)
        u[i] = pack2(tile[cp + 2 * i][d], tile[cp + 2 * i + 1][d]);
    unsigned short* dst = w3t + (size_t)(s * 64 + d) * KDIM + k * 64 + cp;
    *reinterpret_cast<u32x4*>(dst)     = u32x4{u[0], u[1], u[2], u[3]};
    *reinterpret_cast<u32x4*>(dst + 8) = u32x4{u[4], u[5], u[6], u[7]};
}

// ---------- Kernel 3: fused weight-gen + contraction (MFMA, LDS-staged B) ----------
// 736 blocks: main 12s x 3kz x 16bx, gate 5s x 2kz x 16bx. 4 waves x 64 rows, rf=4, cf=4.
// B: per-k-row 8KB staged to LDS via global_load_lds (dbuf), subtile layout ->
//    ds_read_b128 is lane-linear (0 bank conflicts).
__global__ __launch_bounds__(256, 3) void gemm_kernel(
    const float* __restrict__ x, const unsigned short* __restrict__ h2t,
    const unsigned short* __restrict__ w3t,
    float* __restrict__ out, unsigned short* __restrict__ outp,
    float* __restrict__ gatep)
{
    __shared__ __align__(16) unsigned short h2s[65 * 256];
    __shared__ __align__(16) unsigned short Bs[2][4096];   // 2 x 8 KB

    const int t  = threadIdx.x;
    const int w  = t >> 6;
    const int l  = t & 63;
    const int p  = l >> 4;
    const int lr = l & 15;

    // block decode: same-(s,kz) groups land on one XCD (bid%8 inverse map)
    const int bid  = blockIdx.x;
    const int slot = (bid & 7) * 92 + (bid >> 3);   // 736 = 8*92, bijective
    const int grp  = slot >> 4;
    const int bx   = slot & 15;
    int s, kz, k0, nk;
    if (grp < 36) { s = grp / 3; kz = grp % 3; k0 = kz * 43; nk = 43; }
    else { int gg = grp - 36; s = 12 + (gg >> 1); kz = gg & 1; k0 = kz * 65; nk = 65 - kz; }
    const int b0 = bx * 256;
    const int m  = (s < 12) ? s : (s - 12);

    // stage h2^T tile [nk][256 cols]
    {
        const char* h2g = (const char*)(h2t + (size_t)k0 * E + b0);
        const int total = nk * 512;
        for (int lin = t * 16; lin < total; lin += 4096) {
            int kl = lin >> 9, off = lin & 511;
            *reinterpret_cast<u32x4*>((char*)h2s + lin) =
                *reinterpret_cast<const u32x4*>(h2g + (size_t)kl * (E * 2) + off);
        }
    }

    // A fragments: x rows for this wave, bf16-packed, live whole kernel
    u32x4 xa[4][2];
    #pragma unroll
    for (int rf = 0; rf < 4; ++rf)
        #pragma unroll
        for (int s2 = 0; s2 < 2; ++s2) {
            const float* xp = x + (size_t)(b0 + w * 64 + rf * 16 + lr) * (M * C)
                              + m * 64 + s2 * 32 + p * 8;
            float4 a = *reinterpret_cast<const float4*>(xp);
            float4 b = *reinterpret_cast<const float4*>(xp + 4);
            xa[rf][s2] = u32x4{pack2(a.x, a.y), pack2(a.z, a.w),
                               pack2(b.x, b.y), pack2(b.z, b.w)};
        }

    // staging source: wave w stages subtile (cf=w, s2=q); lane l -> (d=w*16+lr, ch=q*4+p)
    const unsigned short* gsrc[2];
    #pragma unroll
    for (int q = 0; q < 2; ++q)
        gsrc[q] = w3t + (size_t)(s * 64 + w * 16 + lr) * KDIM
                  + (size_t)k0 * 64 + (q * 4 + p) * 8;

#define STAGE(buf, kr)                                                          \
    {                                                                           \
        _Pragma("unroll")                                                       \
        for (int q = 0; q < 2; ++q)                                             \
            __builtin_amdgcn_global_load_lds(                                   \
                (gvoid*)(gsrc[q] + (size_t)(kr) * 64),                          \
                (lvoid*)(&Bs[buf][(w * 2 + q) * 512]), 16, 0, 0);               \
    }

    f32x4 acc[4][4];
    #pragma unroll
    for (int a = 0; a < 4; ++a)
        #pragma unroll
        for (int b = 0; b < 4; ++b) acc[a][b] = f32x4{0.f, 0.f, 0.f, 0.f};
    const f32x4 zf = {0.f, 0.f, 0.f, 0.f};

    STAGE(0, 0);
    __syncthreads();

    int cur = 0;
    for (int kr = 0; kr < nk; ++kr) {
        if (kr + 1 < nk) STAGE(cur ^ 1, kr + 1);

        // h2 scalars for this k-row (broadcast LDS reads)
        float h[4][4];
        #pragma unroll
        for (int rf = 0; rf < 4; ++rf) {
            u32x2 hv = *reinterpret_cast<const u32x2*>(
                &h2s[kr * 256 + w * 64 + rf * 16 + p * 4]);
            h[rf][0] = asf(hv.x << 16);
            h[rf][1] = asf(hv.x & 0xFFFF0000u);
            h[rf][2] = asf(hv.y << 16);
            h[rf][3] = asf(hv.y & 0xFFFF0000u);
        }
        #pragma unroll
        for (int cf = 0; cf < 4; ++cf) {
            u32x4 B0 = *reinterpret_cast<const u32x4*>(&Bs[cur][(cf * 2 + 0) * 512 + l * 8]);
            u32x4 B1 = *reinterpret_cast<const u32x4*>(&Bs[cur][(cf * 2 + 1) * 512 + l * 8]);
            #pragma unroll
            for (int rf = 0; rf < 4; ++rf) {
                f32x4 tt = __builtin_amdgcn_mfma_f32_16x16x32_bf16(
                    __builtin_bit_cast(bf16x8, xa[rf][0]),
                    __builtin_bit_cast(bf16x8, B0), zf, 0, 0, 0);
                tt = __builtin_amdgcn_mfma_f32_16x16x32_bf16(
                    __builtin_bit_cast(bf16x8, xa[rf][1]),
                    __builtin_bit_cast(bf16x8, B1), tt, 0, 0, 0);
                acc[rf][cf][0] += h[rf][0] * tt[0];
                acc[rf][cf][1] += h[rf][1] * tt[1];
                acc[rf][cf][2] += h[rf][2] * tt[2];
                acc[rf][cf][3] += h[rf][3] * tt[3];
            }
        }
        __syncthreads();
        cur ^= 1;
    }
#undef STAGE

    if (s < 12) {
        if (kz == 0) {
            #pragma unroll
            for (int rf = 0; rf < 4; ++rf)
                #pragma unroll
                for (int cf = 0; cf < 4; ++cf)
                    #pragma unroll
                    for (int r = 0; r < 4; ++r) {
                        int b = b0 + w * 64 + rf * 16 + p * 4 + r;
                        int d = cf * 16 + lr;
                        out[(size_t)b * (M * D) + s * D + d] = acc[rf][cf][r];
                    }
        } else {
            unsigned short* ob = outp + (size_t)(kz - 1) * (E * M * D);
            #pragma unroll
            for (int rf = 0; rf < 4; ++rf)
                #pragma unroll
                for (int cf = 0; cf < 4; ++cf)
                    #pragma unroll
                    for (int r = 0; r < 4; ++r) {
                        int b = b0 + w * 64 + rf * 16 + p * 4 + r;
                        int d = cf * 16 + lr;
                        ob[(size_t)b * (M * D) + s * D + d] = f2bf(acc[rf][cf][r]);
                    }
        }
    } else {
        float* gp = gatep + (size_t)((s - 12) * 2 + kz) * (E * 64);
        #pragma unroll
        for (int rf = 0; rf < 4; ++rf)
            #pragma unroll
            for (int cf = 0; cf < 4; ++cf)
                #pragma unroll
                for (int r = 0; r < 4; ++r) {
                    int b = b0 + w * 64 + rf * 16 + p * 4 + r;
                    int d = cf * 16 + lr;
                    gp[(size_t)b * 64 + d] = acc[rf][cf][r];
                }
    }
}

// ---------- Kernel 4: out += bf16 partials (main), gate = sum of 10 partials ----------
__global__ __launch_bounds__(256) void reduce_kernel(
    float* __restrict__ out, const unsigned short* __restrict__ outp,
    const float* __restrict__ gatep)
{
    const int MAIN4 = E * M * D / 4;     // 786432
    int i = blockIdx.x * 256 + threadIdx.x;
    if (i < MAIN4) {
        float4 a = reinterpret_cast<float4*>(out)[i];
        u32x2 p0 = *reinterpret_cast<const u32x2*>(outp + (size_t)i * 4);
        u32x2 p1 = *reinterpret_cast<const u32x2*>(outp + (size_t)E * M * D + (size_t)i * 4);
        a.x += asf(p0.x << 16)        + asf(p1.x << 16);
        a.y += asf(p0.x & 0xFFFF0000u) + asf(p1.x & 0xFFFF0000u);
        a.z += asf(p0.y << 16)        + asf(p1.y << 16);
        a.w += asf(p0.y & 0xFFFF0000u) + asf(p1.y & 0xFFFF0000u);
        reinterpret_cast<float4*>(out)[i] = a;
    } else {
        int j = i - MAIN4;               // < 65536
        const float4* g4 = reinterpret_cast<const float4*>(gatep);
        float4 sum = make_float4(0.f, 0.f, 0.f, 0.f);
        #pragma unroll
        for (int q = 0; q < 10; ++q) {
            float4 v = g4[(size_t)q * 65536 + j];
            sum.x += v.x; sum.y += v.y; sum.z += v.z; sum.w += v.w;
        }
        reinterpret_cast<float4*>(out + (size_t)E * M * D)[j] = sum;
    }
}

extern "C" void kernel_launch(void* const* d_in, const int* in_sizes, int n_in,
                              void* d_out, int out_size, void* d_ws, size_t ws_size,
                              hipStream_t stream)
{
    const float* x      = (const float*)d_in[0];
    const float* x_edge = (const float*)d_in[1];
    const float* W1     = (const float*)d_in[2];
    const float* b1     = (const float*)d_in[3];
    const float* W2     = (const float*)d_in[4];
    const float* b2     = (const float*)d_in[5];
    const float* W3     = (const float*)d_in[6];
    const float* b3     = (const float*)d_in[7];

    float* out = (float*)d_out;

    // ws: W3T 17,965,056 | h2t 1,056,768 | outp(bf16 x2) 12,582,912 | gatep 10,485,760
    char* ws = (char*)d_ws;
    unsigned short* w3t   = (unsigned short*)ws;
    unsigned short* h2t   = (unsigned short*)(ws + 17965056);
    unsigned short* outp  = (unsigned short*)(ws + 19021824);
    float*          gatep = (float*)(ws + 31604736);

    mlp_kernel<<<E / 16, 256, 0, stream>>>(x_edge, W1, b1, W2, b2, h2t);
    w3t_kernel<<<dim3(129, NSLICE), 256, 0, stream>>>(W3, b3, w3t);
    gemm_kernel<<<736, 256, 0, stream>>>(x, h2t, w3t, out, outp, gatep);
    reduce_kernel<<<3328, 256, 0, stream>>>(out, outp, gatep);
}